// Round 16
// baseline (1024.435 us; speedup 1.0000x reference)
//
#include <hip/hip_runtime.h>

#define DEV __device__ __forceinline__

typedef unsigned short u16;
typedef __bf16 bf16x8 __attribute__((ext_vector_type(8)));
typedef bf16x8 __attribute__((may_alias)) bf16x8a;
typedef float f32x4 __attribute__((ext_vector_type(4)));
typedef float f32x16 __attribute__((ext_vector_type(16)));

constexpr int NB = 4, NS = 2048, NE = 1024, NH = 4, NDH = 256, NF = 4096;
constexpr int NR = NB * NS;  // 8192 rows

DEV u16 f2bf(float f) {
  unsigned u = __float_as_uint(f);
  u += 0x7fff + ((u >> 16) & 1);
  return (u16)(u >> 16);
}

DEV f32x4 mfma16(bf16x8 a, bf16x8 b, f32x4 c) {
  return __builtin_amdgcn_mfma_f32_16x16x32_bf16(a, b, c, 0, 0, 0);
}
DEV f32x16 mfma32(bf16x8 a, bf16x8 b, f32x16 c) {
  return __builtin_amdgcn_mfma_f32_32x32x16_bf16(a, b, c, 0, 0, 0);
}

DEV bf16x8 ldfrag(const u16* p) { return *(const bf16x8a*)p; }

DEV void gload_lds16(const void* g, void* l) {
  __builtin_amdgcn_global_load_lds(
      (const __attribute__((address_space(1))) void*)g,
      (__attribute__((address_space(3))) void*)l, 16, 0, 0);
}

DEV void blockbar() {
  asm volatile("" ::: "memory");
  __builtin_amdgcn_s_barrier();
  asm volatile("" ::: "memory");
}

DEV unsigned packbf(float a, float b) {
  union { __bf16 h[2]; unsigned u; } x;
  x.h[0] = (__bf16)a; x.h[1] = (__bf16)b;
  return x.u;
}

// ---------------- elementwise cast f32 -> bf16 ----------------
__global__ void cast_f32_bf16(const float* __restrict__ in, u16* __restrict__ out, int n4) {
  int i = blockIdx.x * 256 + threadIdx.x;
  if (i >= n4) return;
  float4 v = ((const float4*)in)[i];
  ushort4 o;
  o.x = f2bf(v.x); o.y = f2bf(v.y); o.z = f2bf(v.z); o.w = f2bf(v.w);
  ((ushort4*)out)[i] = o;
}

// ---------------- batched transpose + cast: in[z][R][C] f32 -> out[z][C][R] bf16 ----------------
__global__ void transpose_cast(const float* __restrict__ in, u16* __restrict__ out, int R, int C) {
  __shared__ float t[32][33];
  size_t base = (size_t)blockIdx.z * R * C;
  int c0 = blockIdx.x * 32, r0 = blockIdx.y * 32;
  int x = threadIdx.x;
  for (int yy = threadIdx.y; yy < 32; yy += 8)
    t[yy][x] = in[base + (size_t)(r0 + yy) * C + c0 + x];
  __syncthreads();
  for (int yy = threadIdx.y; yy < 32; yy += 8)
    out[base + (size_t)(c0 + yy) * R + r0 + x] = f2bf(t[x][yy]);
}

// ---- 6 per-head weights [4][1024][256] -> transposed bf16, one dispatch (z=24) ----
__global__ void transpose_cast6(const float* s0, const float* s1, const float* s2,
                                const float* s3, const float* s4, const float* s5,
                                u16* d0, u16* d1, u16* d2, u16* d3, u16* d4, u16* d5) {
  __shared__ float t[32][33];
  int z = blockIdx.z;
  int widx = z >> 2, hz = z & 3;
  const float* in; u16* out;
  switch (widx) {
    case 0: in = s0; out = d0; break;
    case 1: in = s1; out = d1; break;
    case 2: in = s2; out = d2; break;
    case 3: in = s3; out = d3; break;
    case 4: in = s4; out = d4; break;
    default: in = s5; out = d5; break;
  }
  size_t base = (size_t)hz * NE * NDH;
  int c0 = blockIdx.x * 32, r0 = blockIdx.y * 32;
  int x = threadIdx.x;
  for (int yy = threadIdx.y; yy < 32; yy += 8)
    t[yy][x] = in[base + (size_t)(r0 + yy) * NDH + c0 + x];
  __syncthreads();
  for (int yy = threadIdx.y; yy < 32; yy += 8)
    out[base + (size_t)(c0 + yy) * NE + r0 + x] = f2bf(t[x][yy]);
}

// ---- Wo1+Wo2 [1024][1024] -> transposed bf16, one dispatch (z=2) ----
__global__ void transpose_cast2(const float* s0, const float* s1,
                                u16* d0, u16* d1) {
  __shared__ float t[32][33];
  const float* in = blockIdx.z ? s1 : s0;
  u16* out = blockIdx.z ? d1 : d0;
  int c0 = blockIdx.x * 32, r0 = blockIdx.y * 32;
  int x = threadIdx.x;
  for (int yy = threadIdx.y; yy < 32; yy += 8)
    t[yy][x] = in[(size_t)(r0 + yy) * NE + c0 + x];
  __syncthreads();
  for (int yy = threadIdx.y; yy < 32; yy += 8)
    out[(size_t)(c0 + yy) * NE + r0 + x] = f2bf(t[x][yy]);
}

// ---- all 5 bias vectors (1024 each) packed in one dispatch ----
__global__ void pack_bias(const float* b0, const float* b1, const float* b2,
                          const float* b3, const float* b4,
                          float* BQKV1, float* BKV2) {
  int x = blockIdx.x;             // 0..19
  int seg = x >> 2;
  int i = (x & 3) * 256 + threadIdx.x;
  switch (seg) {
    case 0: BQKV1[i] = b0[i]; break;
    case 1: BQKV1[1024 + i] = b1[i]; break;
    case 2: BQKV1[2048 + i] = b2[i]; break;
    case 3: BKV2[i] = b3[i]; break;
    default: BKV2[1024 + i] = b4[i]; break;
  }
}

// ---------------- V transpose: V[(b*S+s)*vstride + h*DH + d] -> Vt[(bh*DH+d)*S + s] ----------------
__global__ void transpose_v(const u16* __restrict__ V, int vstride, u16* __restrict__ Vt) {
  __shared__ u16 t[32][34];
  int bh = blockIdx.z, b = bh >> 2, h = bh & (NH - 1);
  int s0 = blockIdx.x * 32, d0 = blockIdx.y * 32;
  int x = threadIdx.x;
  for (int yy = threadIdx.y; yy < 32; yy += 8)
    t[yy][x] = V[(size_t)(b * NS + s0 + yy) * vstride + h * NDH + d0 + x];
  __syncthreads();
  for (int yy = threadIdx.y; yy < 32; yy += 8)
    Vt[((size_t)bh * NDH + d0 + yy) * NS + s0 + x] = t[x][yy];
}

// ---------------- 2-block GEMM: C[M,N] = A[M,K] * Bt[N,K]^T (+bias,+res,relu) ----------------
template<int OUTF32, int RELU>
__global__ __launch_bounds__(256, 2)
void gemm2b(const u16* __restrict__ A, const u16* __restrict__ Bt,
            const float* __restrict__ bias, const float* __restrict__ res,
            float* __restrict__ outF, u16* __restrict__ outB,
            int M, int N, int K)
{
  __shared__ __align__(16) u16 smem[32768];   // A [2][128][64] | B [2][128][64]

  int tid = threadIdx.x, w = tid >> 6, lane = tid & 63;
  int lr = lane & 15, lk = lane >> 4;

  int flat = blockIdx.y * gridDim.x + blockIdx.x;
  int cpx = (gridDim.x * gridDim.y) >> 3;
  int swz = (flat & 7) * cpx + (flat >> 3);
  int bx = swz % gridDim.x, by = swz / gridDim.x;
  int rowBlk = by * 128, colBlk = bx * 128;

  f32x4 acc[8][2];
#pragma unroll
  for (int f = 0; f < 8; f++)
#pragma unroll
    for (int n = 0; n < 2; n++) acc[f][n] = (f32x4){0.f, 0.f, 0.f, 0.f};

  int srow = lane >> 3;                       // 0..7
  int scol = ((lane & 7) ^ srow) * 8;         // pre-swizzled source granule

  const u16* gA = A + (size_t)rowBlk * K;
  const u16* gB = Bt + (size_t)colBlk * K;

  auto stageA = [&](int t, int p) {
#pragma unroll
    for (int j = 0; j < 4; j++) {
      int rbase = (w * 4 + j) * 8;
      gload_lds16(gA + (size_t)(rbase + srow) * K + (size_t)t * 64 + scol,
                  &smem[(p * 128 + rbase) * 64]);
    }
  };
  auto stageB = [&](int t, int p) {
#pragma unroll
    for (int j = 0; j < 4; j++) {
      int rbase = (w * 4 + j) * 8;
      gload_lds16(gB + (size_t)(rbase + srow) * K + (size_t)t * 64 + scol,
                  &smem[16384 + (p * 128 + rbase) * 64]);
    }
  };

  stageB(0, 0);
  asm volatile("" ::: "memory");
  stageA(0, 0);
  asm volatile("s_waitcnt vmcnt(0)" ::: "memory");
  blockbar();

  int NT = K >> 6;
  for (int t = 0; t < NT; t++) {
    int p = t & 1;
    if (t + 1 < NT) {
      stageB(t + 1, p ^ 1);
      asm volatile("" ::: "memory");
      stageA(t + 1, p ^ 1);
      asm volatile("" ::: "memory");
    }
    const u16* Ar = &smem[p * 8192];
    const u16* Br = &smem[16384 + p * 8192];
    bf16x8 bf[2][2], af[8][2];
#pragma unroll
    for (int n = 0; n < 2; n++)
#pragma unroll
      for (int s = 0; s < 2; s++) {
        int rowB = w * 32 + n * 16 + lr;
        bf[n][s] = ldfrag(&Br[rowB * 64 + (((s * 4 + lk) ^ (lr & 7)) * 8)]);
      }
#pragma unroll
    for (int f = 0; f < 8; f++)
#pragma unroll
      for (int s = 0; s < 2; s++) {
        int rowA = f * 16 + lr;
        af[f][s] = ldfrag(&Ar[rowA * 64 + (((s * 4 + lk) ^ (lr & 7)) * 8)]);
      }
    __builtin_amdgcn_s_setprio(1);
#pragma unroll
    for (int f = 0; f < 8; f++)
#pragma unroll
      for (int n = 0; n < 2; n++)
#pragma unroll
        for (int s = 0; s < 2; s++)
          acc[f][n] = mfma16(af[f][s], bf[n][s], acc[f][n]);
    __builtin_amdgcn_s_setprio(0);
    asm volatile("s_waitcnt vmcnt(0)" ::: "memory");
    blockbar();
  }

  int ocol0 = colBlk + w * 32;
#pragma unroll
  for (int n = 0; n < 2; n++) {
    int c = ocol0 + n * 16 + lr;
    float bv = bias[c];
#pragma unroll
    for (int f = 0; f < 8; f++) {
      int r0 = rowBlk + f * 16 + lk * 4;
#pragma unroll
      for (int j = 0; j < 4; j++) {
        float v = acc[f][n][j] + bv;
        if (OUTF32) v += res[(size_t)(r0 + j) * N + c];
        if (RELU) v = fmaxf(v, 0.f);
        if (OUTF32) outF[(size_t)(r0 + j) * N + c] = v;
        else        outB[(size_t)(r0 + j) * N + c] = f2bf(v);
      }
    }
  }
}

// ---------------- cross attention: 8 waves, QBLK=128, KBLK=64, double-buffered ----
// grid 256 = 16 bh * 16 qtiles, full key range, writes normalized bf16 O. (verified)
__global__ __launch_bounds__(512, 2)
void attn8w(const u16* __restrict__ Qp, int qstride,
            const u16* __restrict__ Kp, int kstride,
            const u16* __restrict__ Vt, u16* __restrict__ O)
{
  __shared__ __align__(16) u16 smem[65536];   // 128KB

  int bidx = blockIdx.x;
  int bh = bidx & 15;
  int qt = bidx >> 4;
  int kt0 = 0, kt1 = NS / 64;
  int b = bh >> 2, h = bh & 3;
  int tid = threadIdx.x, w = tid >> 6, lane = tid & 63;
  int L = lane & 31, hi = lane >> 5;
  int g = w >> 1, ks = w & 1;

  int qbase = qt * 128 + g * 32;

  const u16* qrow = Qp + (size_t)(b * NS + qbase + L) * qstride + h * NDH;
  bf16x8 qf[16];
#pragma unroll
  for (int s = 0; s < 16; s++) qf[s] = ldfrag(qrow + s * 16 + hi * 8);

  f32x16 oacc[8];
#pragma unroll
  for (int db = 0; db < 8; db++) oacc[db] = (f32x16){};
  float m = -1e30f, l = 0.f;

  constexpr float SC = 1.0f / NDH;

  const u16* kbase = Kp + (size_t)(b * NS) * kstride + h * NDH;
  const u16* vbase = Vt + (size_t)bh * NDH * NS;

  auto stage = [&](int kt, int buf) {
#pragma unroll
    for (int ii = 0; ii < 4; ii++) {
      int gi = w * 4 + ii;                       // 0..31
      int krow = 2 * gi + hi;
      int kcol = L ^ (krow & 31);
      gload_lds16(kbase + (size_t)(kt * 64 + krow) * kstride + kcol * 8,
                  &smem[buf * 16384 + gi * 512]);
      int vd = gi * 8 + (lane >> 3);
      int vg = (lane & 7) ^ (vd & 7);
      gload_lds16(vbase + (size_t)vd * NS + kt * 64 + vg * 8,
                  &smem[32768 + buf * 16384 + gi * 512]);
    }
  };

  stage(kt0, 0);
  asm volatile("" ::: "memory");

  for (int kt = kt0; kt < kt1; kt++) {
    int buf = (kt - kt0) & 1;
    const u16* bK = &smem[buf * 16384];
    const u16* bV = &smem[32768 + buf * 16384];
    if (kt + 1 < kt1) {
      stage(kt + 1, buf ^ 1);
      asm volatile("s_waitcnt vmcnt(8)" ::: "memory");
    } else {
      asm volatile("s_waitcnt vmcnt(0)" ::: "memory");
    }
    blockbar();

    {
      __builtin_amdgcn_s_setprio(1);
      f32x16 sa = (f32x16){};
#pragma unroll
      for (int s = 0; s < 16; s++) {
        int row = ks * 32 + L;
        bf16x8 kf = ldfrag(&bK[row * 256 + (((2 * s + hi) ^ L) & 31) * 8]);
        sa = mfma32(kf, qf[s], sa);
      }
      __builtin_amdgcn_s_setprio(0);

      float p[16];
      float tmax = -1e30f;
#pragma unroll
      for (int r = 0; r < 16; r++) {
        float v = sa[r] * SC;
        p[r] = v;
        tmax = fmaxf(tmax, v);
      }
      tmax = fmaxf(tmax, __shfl_xor(tmax, 32));

      float mn = m;
      if (!__all(tmax - m <= 5.0f)) {
        mn = fmaxf(m, tmax);
        float rs = __expf(m - mn);
        m = mn;
        l *= rs;
#pragma unroll
        for (int db = 0; db < 8; db++)
#pragma unroll
          for (int r = 0; r < 16; r++) oacc[db][r] *= rs;
      }
      float psum = 0.f;
#pragma unroll
      for (int r = 0; r < 16; r++) {
        p[r] = __expf(p[r] - mn);
        psum += p[r];
      }
      psum += __shfl_xor(psum, 32);
      l += psum;

      unsigned pk01 = packbf(p[0], p[1]),  pk23 = packbf(p[2], p[3]);
      unsigned pk45 = packbf(p[4], p[5]),  pk67 = packbf(p[6], p[7]);
      unsigned pk89 = packbf(p[8], p[9]),  pkab = packbf(p[10], p[11]);
      unsigned pkcd = packbf(p[12], p[13]), pkef = packbf(p[14], p[15]);
      unsigned s45 = (unsigned)__shfl_xor((int)pk45, 32);
      unsigned s67 = (unsigned)__shfl_xor((int)pk67, 32);
      unsigned s01 = (unsigned)__shfl_xor((int)pk01, 32);
      unsigned s23 = (unsigned)__shfl_xor((int)pk23, 32);
      unsigned scd = (unsigned)__shfl_xor((int)pkcd, 32);
      unsigned sef = (unsigned)__shfl_xor((int)pkef, 32);
      unsigned s89 = (unsigned)__shfl_xor((int)pk89, 32);
      unsigned sab = (unsigned)__shfl_xor((int)pkab, 32);
      union { unsigned u[4]; bf16x8 v; } fb0, fb1;
      fb0.u[0] = hi ? s45 : pk01;
      fb0.u[1] = hi ? s67 : pk23;
      fb0.u[2] = hi ? pk45 : s01;
      fb0.u[3] = hi ? pk67 : s23;
      fb1.u[0] = hi ? scd : pk89;
      fb1.u[1] = hi ? sef : pkab;
      fb1.u[2] = hi ? pkcd : s89;
      fb1.u[3] = hi ? pkef : sab;
      bf16x8 pb0 = fb0.v, pb1 = fb1.v;

      __builtin_amdgcn_s_setprio(1);
#pragma unroll
      for (int db = 0; db < 8; db++) {
        int vd = db * 32 + L;
        bf16x8 vf0 = ldfrag(&bV[vd * 64 + (((ks * 4 + hi) ^ (vd & 7)) & 7) * 8]);
        bf16x8 vf1 = ldfrag(&bV[vd * 64 + (((ks * 4 + 2 + hi) ^ (vd & 7)) & 7) * 8]);
        oacc[db] = mfma32(vf0, pb0, oacc[db]);
        oacc[db] = mfma32(vf1, pb1, oacc[db]);
      }
      __builtin_amdgcn_s_setprio(0);
    }
    blockbar();
  }

  // ---- merge wave pairs ----
  float* fsm = (float*)smem;
  blockbar();
  if (hi == 0) { fsm[w * 64 + L * 2] = m; fsm[w * 64 + L * 2 + 1] = l; }
  asm volatile("s_waitcnt lgkmcnt(0)" ::: "memory");
  blockbar();
  float mb = fsm[(w ^ 1) * 64 + L * 2];
  float lb = fsm[(w ^ 1) * 64 + L * 2 + 1];
  float M = fmaxf(m, mb);
  float eo = __expf(m - M);
  float lt = l * eo + lb * __expf(mb - M);
  asm volatile("s_waitcnt lgkmcnt(0)" ::: "memory");
  blockbar();
  float* reg = fsm + g * 8192;   // 32KB region per pair: [256 d][32 q] f32
  if (w & 1) {
#pragma unroll
    for (int db = 0; db < 8; db++)
#pragma unroll
      for (int r = 0; r < 16; r++) {
        int d = db * 32 + (r & 3) + 8 * (r >> 2) + 4 * hi;
        reg[d * 32 + L] = oacc[db][r] * eo;
      }
  }
  asm volatile("s_waitcnt lgkmcnt(0)" ::: "memory");
  blockbar();
  if (!(w & 1)) {
    float inv = 1.f / lt;
    size_t orow = (size_t)(b * NS + qbase + L) * NE + h * NDH;
#pragma unroll
    for (int db = 0; db < 8; db++) {
#pragma unroll
      for (int rq = 0; rq < 4; rq++) {
        int d0 = db * 32 + rq * 8 + hi * 4;
        float a0 = (oacc[db][rq * 4 + 0] * eo + reg[(d0 + 0) * 32 + L]) * inv;
        float a1 = (oacc[db][rq * 4 + 1] * eo + reg[(d0 + 1) * 32 + L]) * inv;
        float a2 = (oacc[db][rq * 4 + 2] * eo + reg[(d0 + 2) * 32 + L]) * inv;
        float a3 = (oacc[db][rq * 4 + 3] * eo + reg[(d0 + 3) * 32 + L]) * inv;
        uint2 wv;
        wv.x = packbf(a0, a1);
        wv.y = packbf(a2, a3);
        *(uint2*)&O[orow + d0] = wv;
      }
    }
  }
}

// ---------------- causal split attention: single-buffered 64KB -> 2 blocks/CU ----
// grid 512 = 16 qt(desc) * 2 half * 16 bh; writes unnormalized f32 partials + (m,l).
// R10-verified 4-barrier rotation (per-wave stage = 4 K + 4 V instrs, vmcnt(4)
// counted, vmcnt(0) on last); merge in 2 half-d rounds (64KB scratch).
__global__ __launch_bounds__(512, 4)
void attn8w_sb(const u16* __restrict__ Qp, int qstride,
               const u16* __restrict__ Kp, int kstride,
               const u16* __restrict__ Vt,
               float* __restrict__ Op, float* __restrict__ ml)
{
  __shared__ __align__(16) u16 smem[32768];   // 64KB: K [64][256] | V^T [256][64]

  int bidx = blockIdx.x;
  int qtIdx = bidx >> 5;         // 0..15, longest-first
  int qt = 15 - qtIdx;
  int sub = bidx & 31;
  int half0 = sub >> 4;
  int bh = sub & 15;
  int kt0 = half0 ? (qt + 1) : 0;
  int kt1 = half0 ? (2 * qt + 2) : (qt + 1);
  int b = bh >> 2, h = bh & 3;
  int tid = threadIdx.x, w = tid >> 6, lane = tid & 63;
  int L = lane & 31, hi = lane >> 5;
  int g = w >> 1, ks = w & 1;

  int qbase = qt * 128 + g * 32;

  const u16* qrow = Qp + (size_t)(b * NS + qbase + L) * qstride + h * NDH;
  bf16x8 qf[16];
#pragma unroll
  for (int s = 0; s < 16; s++) qf[s] = ldfrag(qrow + s * 16 + hi * 8);

  f32x16 oacc[8];
#pragma unroll
  for (int db = 0; db < 8; db++) oacc[db] = (f32x16){};
  float m = -1e30f, l = 0.f;

  constexpr float SC = 1.0f / NDH;

  const u16* kbase = Kp + (size_t)(b * NS) * kstride + h * NDH;
  const u16* vbase = Vt + (size_t)bh * NDH * NS;

  auto stageK = [&](int kt) {
#pragma unroll
    for (int ii = 0; ii < 4; ii++) {
      int gi = w * 4 + ii;                       // 0..31
      int krow = 2 * gi + hi;
      int kcol = L ^ (krow & 31);
      gload_lds16(kbase + (size_t)(kt * 64 + krow) * kstride + kcol * 8,
                  &smem[gi * 512]);
    }
  };
  auto stageV = [&](int kt) {
#pragma unroll
    for (int ii = 0; ii < 4; ii++) {
      int gi = w * 4 + ii;
      int vd = gi * 8 + (lane >> 3);
      int vg = (lane & 7) ^ (vd & 7);
      gload_lds16(vbase + (size_t)vd * NS + kt * 64 + vg * 8,
                  &smem[16384 + gi * 512]);
    }
  };

  stageK(kt0);
  asm volatile("" ::: "memory");
  stageV(kt0);
  asm volatile("s_waitcnt vmcnt(0)" ::: "memory");
  blockbar();

  for (int kt = kt0; kt < kt1; kt++) {
    bool last = (kt + 1 == kt1);
    int ksub0 = kt * 64 + ks * 32;
    bool skip = (ksub0 > qbase + 31);
    bool domask = !skip && (ksub0 + 31 > qbase);

    f32x16 sa = (f32x16){};
    if (!skip) {
      __builtin_amdgcn_s_setprio(1);
#pragma unroll
      for (int s = 0; s < 16; s++) {
        int row = ks * 32 + L;
        bf16x8 kf = ldfrag(&smem[row * 256 + (((2 * s + hi) ^ L) & 31) * 8]);
        sa = mfma32(kf, qf[s], sa);
      }
      __builtin_amdgcn_s_setprio(0);
    }
    blockbar();                                  // lK free
    if (!last) stageK(kt + 1);                   // K latency hides under softmax

    bf16x8 pb0, pb1;
    if (!skip) {
      float p[16];
      float tmax = -1e30f;
#pragma unroll
      for (int r = 0; r < 16; r++) {
        float v = sa[r] * SC;
        if (domask) {
          int key = ksub0 + (r & 3) + 8 * (r >> 2) + 4 * hi;
          if (key > qbase + L) v = -1e30f;
        }
        p[r] = v;
        tmax = fmaxf(tmax, v);
      }
      tmax = fmaxf(tmax, __shfl_xor(tmax, 32));

      float mn = m;
      if (!__all(tmax - m <= 5.0f)) {
        mn = fmaxf(m, tmax);
        float rs = __expf(m - mn);
        m = mn;
        l *= rs;
#pragma unroll
        for (int db = 0; db < 8; db++)
#pragma unroll
          for (int r = 0; r < 16; r++) oacc[db][r] *= rs;
      }
      float psum = 0.f;
#pragma unroll
      for (int r = 0; r < 16; r++) {
        p[r] = __expf(p[r] - mn);
        psum += p[r];
      }
      psum += __shfl_xor(psum, 32);
      l += psum;

      unsigned pk01 = packbf(p[0], p[1]),  pk23 = packbf(p[2], p[3]);
      unsigned pk45 = packbf(p[4], p[5]),  pk67 = packbf(p[6], p[7]);
      unsigned pk89 = packbf(p[8], p[9]),  pkab = packbf(p[10], p[11]);
      unsigned pkcd = packbf(p[12], p[13]), pkef = packbf(p[14], p[15]);
      unsigned s45 = (unsigned)__shfl_xor((int)pk45, 32);
      unsigned s67 = (unsigned)__shfl_xor((int)pk67, 32);
      unsigned s01 = (unsigned)__shfl_xor((int)pk01, 32);
      unsigned s23 = (unsigned)__shfl_xor((int)pk23, 32);
      unsigned scd = (unsigned)__shfl_xor((int)pkcd, 32);
      unsigned sef = (unsigned)__shfl_xor((int)pkef, 32);
      unsigned s89 = (unsigned)__shfl_xor((int)pk89, 32);
      unsigned sab = (unsigned)__shfl_xor((int)pkab, 32);
      union { unsigned u[4]; bf16x8 v; } fb0, fb1;
      fb0.u[0] = hi ? s45 : pk01;
      fb0.u[1] = hi ? s67 : pk23;
      fb0.u[2] = hi ? pk45 : s01;
      fb0.u[3] = hi ? pk67 : s23;
      fb1.u[0] = hi ? scd : pk89;
      fb1.u[1] = hi ? sef : pkab;
      fb1.u[2] = hi ? pkcd : s89;
      fb1.u[3] = hi ? pkef : sab;
      pb0 = fb0.v; pb1 = fb1.v;
    }

    if (!last) asm volatile("s_waitcnt vmcnt(4)" ::: "memory");  // V(kt) ready
    else       asm volatile("s_waitcnt vmcnt(0)" ::: "memory");
    blockbar();

    if (!skip) {
      __builtin_amdgcn_s_setprio(1);
#pragma unroll
      for (int db = 0; db < 8; db++) {
        int vd = db * 32 + L;
        bf16x8 vf0 = ldfrag(&smem[16384 + vd * 64 + (((ks * 4 + hi) ^ (vd & 7)) & 7) * 8]);
        bf16x8 vf1 = ldfrag(&smem[16384 + vd * 64 + (((ks * 4 + 2 + hi) ^ (vd & 7)) & 7) * 8]);
        oacc[db] = mfma32(vf0, pb0, oacc[db]);
        oacc[db] = mfma32(vf1, pb1, oacc[db]);
      }
      __builtin_amdgcn_s_setprio(0);
    }
    blockbar();                                  // lV free
    if (!last) {
      stageV(kt + 1);
      asm volatile("s_waitcnt vmcnt(4)" ::: "memory");  // K(kt+1) ready
      blockbar();
    }
  }

  // ---- merge wave pairs, 2 half-d rounds (64KB scratch) ----
  float* fsm = (float*)smem;
  blockbar();
  if (hi == 0) { fsm[w * 64 + L * 2] = m; fsm[w * 64 + L * 2 + 1] = l; }
  asm volatile("s_waitcnt lgkmcnt(0)" ::: "memory");
  blockbar();
  float mb = fsm[(w ^ 1) * 64 + L * 2];
  float lb = fsm[(w ^ 1) * 64 + L * 2 + 1];
  float M = fmaxf(m, mb);
  float eo = __expf(m - M);
  float lt = l * eo + lb * __expf(mb - M);
  if (hi == 0 && !(w & 1)) {
    ml[((size_t)bidx * 128 + g * 32 + L) * 2]     = M;
    ml[((size_t)bidx * 128 + g * 32 + L) * 2 + 1] = lt;
  }
  float* reg = fsm + g * 4096;   // 16KB per pair: [128 d][32 q] f32
#pragma unroll
  for (int half = 0; half < 2; half++) {
    asm volatile("s_waitcnt lgkmcnt(0)" ::: "memory");
    blockbar();
    if (w & 1) {
#pragma unroll
      for (int db = 0; db < 4; db++) {
#pragma unroll
        for (int r = 0; r < 16; r++) {
          int d = db * 32 + (r & 3) + 8 * (r >> 2) + 4 * hi;   // relative in half
          reg[d * 32 + L] = oacc[half * 4 + db][r] * eo;
        }
      }
    }
    asm volatile("s_waitcnt lgkmcnt(0)" ::: "memory");
    blockbar();
    if (!(w & 1)) {
      float* OpB = Op + (size_t)bidx * 32768 + (size_t)(g * 32 + L) * 256 + half * 128;
#pragma unroll
      for (int db = 0; db < 4; db++) {
#pragma unroll
        for (int rq = 0; rq < 4; rq++) {
          int d0 = db * 32 + rq * 8 + hi * 4;                  // relative in half
          float4 v;
          v.x = oacc[half * 4 + db][rq * 4 + 0] * eo + reg[(d0 + 0) * 32 + L];
          v.y = oacc[half * 4 + db][rq * 4 + 1] * eo + reg[(d0 + 1) * 32 + L];
          v.z = oacc[half * 4 + db][rq * 4 + 2] * eo + reg[(d0 + 2) * 32 + L];
          v.w = oacc[half * 4 + db][rq * 4 + 3] * eo + reg[(d0 + 3) * 32 + L];
          *(float4*)(OpB + d0) = v;
        }
      }
    }
  }
}

// ---------------- merge the 2 split-K partials -> normalized bf16 O ----------------
__global__ __launch_bounds__(256)
void merge_attn(const float* __restrict__ Op, const float* __restrict__ ml,
                u16* __restrict__ O)
{
  int blk = blockIdx.x;
  int qt = blk >> 4, bh = blk & 15;
  int b = bh >> 2, h = bh & 3;
  int p0 = (15 - qt) * 32 + bh;
  int p1 = p0 + 16;
  int tid = threadIdx.x;
  int row = tid >> 1;
  int dbase = (tid & 1) * 128;

  float m0 = ml[((size_t)p0 * 128 + row) * 2];
  float l0 = ml[((size_t)p0 * 128 + row) * 2 + 1];
  float m1 = ml[((size_t)p1 * 128 + row) * 2];
  float l1 = ml[((size_t)p1 * 128 + row) * 2 + 1];
  float M = fmaxf(m0, m1);
  float e0 = __expf(m0 - M), e1 = __expf(m1 - M);
  float inv = 1.f / (l0 * e0 + l1 * e1);
  const float* O0 = Op + ((size_t)p0 * 128 + row) * 256 + dbase;
  const float* O1 = Op + ((size_t)p1 * 128 + row) * 256 + dbase;
  u16* dst = O + (size_t)(b * NS + qt * 128 + row) * NE + h * NDH + dbase;
#pragma unroll
  for (int d = 0; d < 128; d += 4) {
    float4 a = *(const float4*)(O0 + d);
    float4 c = *(const float4*)(O1 + d);
    uint2 wv;
    wv.x = packbf((a.x * e0 + c.x * e1) * inv, (a.y * e0 + c.y * e1) * inv);
    wv.y = packbf((a.z * e0 + c.z * e1) * inv, (a.w * e0 + c.w * e1) * inv);
    *(uint2*)(dst + d) = wv;
  }
}

// ---------------- LayerNorm (eps=1e-3), optional relu, optional bf16 copy ----------------
template<int RELU, int WBF>
__global__ __launch_bounds__(256)
void ln_kernel(const float* __restrict__ x, const float* __restrict__ g,
               const float* __restrict__ bb, float* __restrict__ outF,
               u16* __restrict__ outB)
{
  int row = blockIdx.x, tid = threadIdx.x;
  float4 v = ((const float4*)(x + (size_t)row * NE))[tid];
  float s = v.x + v.y + v.z + v.w;
  float s2 = v.x * v.x + v.y * v.y + v.z * v.z + v.w * v.w;
#pragma unroll
  for (int off = 32; off; off >>= 1) {
    s += __shfl_xor(s, off);
    s2 += __shfl_xor(s2, off);
  }
  __shared__ float red[8];
  int wid = tid >> 6, lane = tid & 63;
  if (lane == 0) { red[wid] = s; red[4 + wid] = s2; }
  __syncthreads();
  s = red[0] + red[1] + red[2] + red[3];
  s2 = red[4] + red[5] + red[6] + red[7];
  float mean = s * (1.f / NE);
  float var = s2 * (1.f / NE) - mean * mean;
  float rstd = rsqrtf(var + 1e-3f);
  float4 gg = ((const float4*)g)[tid];
  float4 bv = ((const float4*)bb)[tid];
  float4 o;
  o.x = (v.x - mean) * rstd * gg.x + bv.x;
  o.y = (v.y - mean) * rstd * gg.y + bv.y;
  o.z = (v.z - mean) * rstd * gg.z + bv.z;
  o.w = (v.w - mean) * rstd * gg.w + bv.w;
  if (RELU) {
    o.x = fmaxf(o.x, 0.f); o.y = fmaxf(o.y, 0.f);
    o.z = fmaxf(o.z, 0.f); o.w = fmaxf(o.w, 0.f);
  }
  ((float4*)(outF + (size_t)row * NE))[tid] = o;
  if (WBF) {
    ushort4 ob;
    ob.x = f2bf(o.x); ob.y = f2bf(o.y); ob.z = f2bf(o.z); ob.w = f2bf(o.w);
    ((ushort4*)(outB + (size_t)row * NE))[tid] = ob;
  }
}

// ---------------- workspace layout (bytes) ----------------
constexpr size_t OFF_X    = 0;                       // 16 MB: Xbf -> O1 -> Ctxbf -> O2
constexpr size_t OFF_W    = OFF_X + 16777216;        // 32 MB packed weights
constexpr size_t OFF_BIAS = OFF_W + 33554432;        // packed biases
constexpr size_t OFF_QKV  = OFF_BIAS + 32768;        // 48 MB QKV1 / (KV2 + Q2) / MID
constexpr size_t OFF_VT   = OFF_QKV + 50331648;      // 16 MB Vt
constexpr size_t OFF_T0   = OFF_VT + 16777216;       // 32 MB f32 scratch; +Af = 64MB Op during attn1
constexpr size_t OFF_A    = OFF_T0 + 33554432;       // 32 MB f32 a / c
constexpr size_t OFF_ABF  = OFF_A + 33554432;        // 16 MB bf16 a / c; ml during attn1

extern "C" void kernel_launch(void* const* d_in, const int* in_sizes, int n_in,
                              void* d_out, int out_size, void* d_ws, size_t ws_size,
                              hipStream_t stream) {
  (void)in_sizes; (void)n_in; (void)out_size; (void)ws_size;
  const float* inp = (const float*)d_in[0];
  const float* ctx = (const float*)d_in[1];
  const float* Wk1 = (const float*)d_in[2];  const float* bk1 = (const float*)d_in[3];
  const float* Wq1 = (const float*)d_in[4];  const float* bq1 = (const float*)d_in[5];
  const float* Wv1 = (const float*)d_in[6];  const float* bv1 = (const float*)d_in[7];
  const float* Wo1 = (const float*)d_in[8];  const float* bo1 = (const float*)d_in[9];
  const float* Wk2 = (const float*)d_in[10]; const float* bk2 = (const float*)d_in[11];
  const float* Wq2 = (const float*)d_in[12]; const float* bq2 = (const float*)d_in[13];
  const float* Wv2 = (const float*)d_in[14]; const float* bv2 = (const float*)d_in[15];
  const float* Wo2 = (const float*)d_in[16]; const float* bo2 = (const float*)d_in[17];
  const float* lng = (const float*)d_in[18]; const float* lnb = (const float*)d_in[19];
  const float* W1  = (const float*)d_in[20]; const float* b1  = (const float*)d_in[21];
  const float* W2  = (const float*)d_in[22]; const float* b2  = (const float*)d_in[23];
  float* out = (float*)d_out;
  char* ws = (char*)d_ws;

  u16* XBF    = (u16*)(ws + OFF_X);        // also ctx-bf16 and attention-O buffer
  u16* WQKV1T = (u16*)(ws + OFF_W);        // rows [K|Q|V] x 1024
  u16* WKV2T  = WQKV1T + 3072 * 1024;      // rows [K|V] x 1024
  u16* WQ2T   = WKV2T + 2048 * 1024;
  u16* WO1T   = WQ2T + 1024 * 1024;
  u16* WO2T   = WO1T + 1024 * 1024;
  u16* W1T    = WO2T + 1024 * 1024;        // [4096][1024]
  u16* W2T    = W1T + 4096 * 1024;         // [1024][4096]
  float* BQKV1 = (float*)(ws + OFF_BIAS);  // 3072
  float* BKV2  = BQKV1 + 3072;             // 2048
  u16* QKV  = (u16*)(ws + OFF_QKV);        // [8192][3072] (self) / [8192][2048] KV2
  u16* Q2   = QKV + 8192 * 2048;           // [8192][1024]
  u16* VT   = (u16*)(ws + OFF_VT);         // [16][256][2048]
  u16* MID  = QKV;                         // [8192][4096] (aliases QKV+VT, both dead)
  float* T0 = (float*)(ws + OFF_T0);
  float* OpBuf = T0;                       // 64MB partial O (T0+Af, both dead in attn1)
  float* Af = (float*)(ws + OFF_A);
  u16* ABF  = (u16*)(ws + OFF_ABF);
  float* MlBuf = (float*)(ws + OFF_ABF);   // 512KB (ABF dead in attn1)
  u16* Obuf = XBF;

  dim3 tb(32, 8);

  // input cast + packed weight/bias preprocessing (5 dispatches)
  cast_f32_bf16<<<8192, 256, 0, stream>>>(inp, XBF, NR * NE / 4);
  transpose_cast6<<<dim3(8, 32, 24), tb, 0, stream>>>(
      Wk1, Wq1, Wv1, Wk2, Wv2, Wq2,
      WQKV1T, WQKV1T + 1024 * 1024, WQKV1T + 2048 * 1024,
      WKV2T, WKV2T + 1024 * 1024, WQ2T);
  transpose_cast2<<<dim3(32, 32, 2), tb, 0, stream>>>(Wo1, Wo2, WO1T, WO2T);
  transpose_cast<<<dim3(128, 32, 1), tb, 0, stream>>>(W1, W1T, NE, NF);
  transpose_cast<<<dim3(32, 128, 1), tb, 0, stream>>>(W2, W2T, NF, NE);
  pack_bias<<<20, 256, 0, stream>>>(bk1, bq1, bv1, bk2, bv2, BQKV1, BKV2);

  // ---- self-attention block (split-K balanced causal, 2 blocks/CU) ----
  gemm2b<0, 0><<<dim3(24, 64), 256, 0, stream>>>(XBF, WQKV1T, BQKV1, nullptr,
                                                 nullptr, QKV, NR, 3072, NE);
  transpose_v<<<dim3(64, 8, 16), tb, 0, stream>>>(QKV + 2048, 3072, VT);
  attn8w_sb<<<512, 512, 0, stream>>>(QKV + 1024, 3072, QKV, 3072, VT,
                                     OpBuf, MlBuf);
  merge_attn<<<256, 256, 0, stream>>>(OpBuf, MlBuf, Obuf);
  gemm2b<1, 0><<<dim3(8, 64), 256, 0, stream>>>(Obuf, WO1T, bo1, inp,
                                                T0, nullptr, NR, NE, NE);
  ln_kernel<0, 1><<<NR, 256, 0, stream>>>(T0, lng, lnb, Af, ABF);

  // ---- cross-attention block ----
  cast_f32_bf16<<<8192, 256, 0, stream>>>(ctx, XBF, NR * NE / 4);
  gemm2b<0, 0><<<dim3(16, 64), 256, 0, stream>>>(XBF, WKV2T, BKV2, nullptr,
                                                 nullptr, QKV, NR, 2048, NE);
  gemm2b<0, 0><<<dim3(8, 64), 256, 0, stream>>>(ABF, WQ2T, bq2, nullptr,
                                                nullptr, Q2, NR, NE, NE);
  transpose_v<<<dim3(64, 8, 16), tb, 0, stream>>>(QKV + 1024, 2048, VT);
  attn8w<<<256, 512, 0, stream>>>(Q2, 1024, QKV, 2048, VT, Obuf);
  gemm2b<1, 0><<<dim3(8, 64), 256, 0, stream>>>(Obuf, WO2T, bo2, Af,
                                                T0, nullptr, NR, NE, NE);
  ln_kernel<0, 1><<<NR, 256, 0, stream>>>(T0, lng, lnb, Af, ABF);

  // ---- FFN ----
  gemm2b<0, 1><<<dim3(32, 64), 256, 0, stream>>>(ABF, W1T, b1, nullptr,
                                                 nullptr, MID, NR, NF, NE);
  gemm2b<1, 0><<<dim3(8, 64), 256, 0, stream>>>(MID, W2T, b2, Af,
                                                T0, nullptr, NR, NE, NF);
  ln_kernel<1, 0><<<NR, 256, 0, stream>>>(T0, lng, lnb, out, nullptr);
}

// Round 17
// 697.741 us; speedup vs baseline: 1.4682x; 1.4682x over previous
//
#include <hip/hip_runtime.h>

#define DEV __device__ __forceinline__

typedef unsigned short u16;
typedef __bf16 bf16x8 __attribute__((ext_vector_type(8)));
typedef bf16x8 __attribute__((may_alias)) bf16x8a;
typedef float f32x4 __attribute__((ext_vector_type(4)));
typedef float f32x16 __attribute__((ext_vector_type(16)));

constexpr int NB = 4, NS = 2048, NE = 1024, NH = 4, NDH = 256, NF = 4096;
constexpr int NR = NB * NS;  // 8192 rows

DEV u16 f2bf(float f) {
  unsigned u = __float_as_uint(f);
  u += 0x7fff + ((u >> 16) & 1);
  return (u16)(u >> 16);
}

DEV f32x4 mfma16(bf16x8 a, bf16x8 b, f32x4 c) {
  return __builtin_amdgcn_mfma_f32_16x16x32_bf16(a, b, c, 0, 0, 0);
}
DEV f32x16 mfma32(bf16x8 a, bf16x8 b, f32x16 c) {
  return __builtin_amdgcn_mfma_f32_32x32x16_bf16(a, b, c, 0, 0, 0);
}

DEV bf16x8 ldfrag(const u16* p) { return *(const bf16x8a*)p; }

DEV void gload_lds16(const void* g, void* l) {
  __builtin_amdgcn_global_load_lds(
      (const __attribute__((address_space(1))) void*)g,
      (__attribute__((address_space(3))) void*)l, 16, 0, 0);
}

DEV void blockbar() {
  asm volatile("" ::: "memory");
  __builtin_amdgcn_s_barrier();
  asm volatile("" ::: "memory");
}

DEV unsigned packbf(float a, float b) {
  union { __bf16 h[2]; unsigned u; } x;
  x.h[0] = (__bf16)a; x.h[1] = (__bf16)b;
  return x.u;
}

// ---------------- elementwise cast f32 -> bf16 ----------------
__global__ void cast_f32_bf16(const float* __restrict__ in, u16* __restrict__ out, int n4) {
  int i = blockIdx.x * 256 + threadIdx.x;
  if (i >= n4) return;
  float4 v = ((const float4*)in)[i];
  ushort4 o;
  o.x = f2bf(v.x); o.y = f2bf(v.y); o.z = f2bf(v.z); o.w = f2bf(v.w);
  ((ushort4*)out)[i] = o;
}

// ---------------- batched transpose + cast: in[z][R][C] f32 -> out[z][C][R] bf16 ----------------
__global__ void transpose_cast(const float* __restrict__ in, u16* __restrict__ out, int R, int C) {
  __shared__ float t[32][33];
  size_t base = (size_t)blockIdx.z * R * C;
  int c0 = blockIdx.x * 32, r0 = blockIdx.y * 32;
  int x = threadIdx.x;
  for (int yy = threadIdx.y; yy < 32; yy += 8)
    t[yy][x] = in[base + (size_t)(r0 + yy) * C + c0 + x];
  __syncthreads();
  for (int yy = threadIdx.y; yy < 32; yy += 8)
    out[base + (size_t)(c0 + yy) * R + r0 + x] = f2bf(t[x][yy]);
}

// ---- 6 per-head weights [4][1024][256] -> transposed bf16, one dispatch (z=24) ----
__global__ void transpose_cast6(const float* s0, const float* s1, const float* s2,
                                const float* s3, const float* s4, const float* s5,
                                u16* d0, u16* d1, u16* d2, u16* d3, u16* d4, u16* d5) {
  __shared__ float t[32][33];
  int z = blockIdx.z;
  int widx = z >> 2, hz = z & 3;
  const float* in; u16* out;
  switch (widx) {
    case 0: in = s0; out = d0; break;
    case 1: in = s1; out = d1; break;
    case 2: in = s2; out = d2; break;
    case 3: in = s3; out = d3; break;
    case 4: in = s4; out = d4; break;
    default: in = s5; out = d5; break;
  }
  size_t base = (size_t)hz * NE * NDH;
  int c0 = blockIdx.x * 32, r0 = blockIdx.y * 32;
  int x = threadIdx.x;
  for (int yy = threadIdx.y; yy < 32; yy += 8)
    t[yy][x] = in[base + (size_t)(r0 + yy) * NDH + c0 + x];
  __syncthreads();
  for (int yy = threadIdx.y; yy < 32; yy += 8)
    out[base + (size_t)(c0 + yy) * NE + r0 + x] = f2bf(t[x][yy]);
}

// ---- Wo1+Wo2 [1024][1024] -> transposed bf16, one dispatch (z=2) ----
__global__ void transpose_cast2(const float* s0, const float* s1,
                                u16* d0, u16* d1) {
  __shared__ float t[32][33];
  const float* in = blockIdx.z ? s1 : s0;
  u16* out = blockIdx.z ? d1 : d0;
  int c0 = blockIdx.x * 32, r0 = blockIdx.y * 32;
  int x = threadIdx.x;
  for (int yy = threadIdx.y; yy < 32; yy += 8)
    t[yy][x] = in[(size_t)(r0 + yy) * NE + c0 + x];
  __syncthreads();
  for (int yy = threadIdx.y; yy < 32; yy += 8)
    out[(size_t)(c0 + yy) * NE + r0 + x] = f2bf(t[x][yy]);
}

// ---- all 5 bias vectors (1024 each) packed in one dispatch ----
__global__ void pack_bias(const float* b0, const float* b1, const float* b2,
                          const float* b3, const float* b4,
                          float* BQKV1, float* BKV2) {
  int x = blockIdx.x;             // 0..19
  int seg = x >> 2;
  int i = (x & 3) * 256 + threadIdx.x;
  switch (seg) {
    case 0: BQKV1[i] = b0[i]; break;
    case 1: BQKV1[1024 + i] = b1[i]; break;
    case 2: BQKV1[2048 + i] = b2[i]; break;
    case 3: BKV2[i] = b3[i]; break;
    default: BKV2[1024 + i] = b4[i]; break;
  }
}

// ---------------- V transpose: V[(b*S+s)*vstride + h*DH + d] -> Vt[(bh*DH+d)*S + s] ----------------
__global__ void transpose_v(const u16* __restrict__ V, int vstride, u16* __restrict__ Vt) {
  __shared__ u16 t[32][34];
  int bh = blockIdx.z, b = bh >> 2, h = bh & (NH - 1);
  int s0 = blockIdx.x * 32, d0 = blockIdx.y * 32;
  int x = threadIdx.x;
  for (int yy = threadIdx.y; yy < 32; yy += 8)
    t[yy][x] = V[(size_t)(b * NS + s0 + yy) * vstride + h * NDH + d0 + x];
  __syncthreads();
  for (int yy = threadIdx.y; yy < 32; yy += 8)
    Vt[((size_t)bh * NDH + d0 + yy) * NS + s0 + x] = t[x][yy];
}

// ---------------- 2-block GEMM: C[M,N] = A[M,K] * Bt[N,K]^T (+bias,+res,relu) ----------------
// BM=128, BN=128, BK=64, 256 threads (4 waves), 64KB LDS -> 2 blocks/CU.
// ONE barrier + ONE vmcnt(0) per K-tile; stage(t+1) issued FIRST (max slack).
template<int OUTF32, int RELU>
__global__ __launch_bounds__(256, 2)
void gemm2b(const u16* __restrict__ A, const u16* __restrict__ Bt,
            const float* __restrict__ bias, const float* __restrict__ res,
            float* __restrict__ outF, u16* __restrict__ outB,
            int M, int N, int K)
{
  __shared__ __align__(16) u16 smem[32768];   // A [2][128][64] | B [2][128][64]

  int tid = threadIdx.x, w = tid >> 6, lane = tid & 63;
  int lr = lane & 15, lk = lane >> 4;

  int flat = blockIdx.y * gridDim.x + blockIdx.x;
  int cpx = (gridDim.x * gridDim.y) >> 3;
  int swz = (flat & 7) * cpx + (flat >> 3);
  int bx = swz % gridDim.x, by = swz / gridDim.x;
  int rowBlk = by * 128, colBlk = bx * 128;

  f32x4 acc[8][2];
#pragma unroll
  for (int f = 0; f < 8; f++)
#pragma unroll
    for (int n = 0; n < 2; n++) acc[f][n] = (f32x4){0.f, 0.f, 0.f, 0.f};

  int srow = lane >> 3;                       // 0..7
  int scol = ((lane & 7) ^ srow) * 8;         // pre-swizzled source granule

  const u16* gA = A + (size_t)rowBlk * K;
  const u16* gB = Bt + (size_t)colBlk * K;

  auto stageA = [&](int t, int p) {
#pragma unroll
    for (int j = 0; j < 4; j++) {
      int rbase = (w * 4 + j) * 8;
      gload_lds16(gA + (size_t)(rbase + srow) * K + (size_t)t * 64 + scol,
                  &smem[(p * 128 + rbase) * 64]);
    }
  };
  auto stageB = [&](int t, int p) {
#pragma unroll
    for (int j = 0; j < 4; j++) {
      int rbase = (w * 4 + j) * 8;
      gload_lds16(gB + (size_t)(rbase + srow) * K + (size_t)t * 64 + scol,
                  &smem[16384 + (p * 128 + rbase) * 64]);
    }
  };

  stageB(0, 0);
  asm volatile("" ::: "memory");
  stageA(0, 0);
  asm volatile("s_waitcnt vmcnt(0)" ::: "memory");
  blockbar();

  int NT = K >> 6;
  for (int t = 0; t < NT; t++) {
    int p = t & 1;
    if (t + 1 < NT) {
      stageB(t + 1, p ^ 1);
      asm volatile("" ::: "memory");
      stageA(t + 1, p ^ 1);
      asm volatile("" ::: "memory");
    }
    const u16* Ar = &smem[p * 8192];
    const u16* Br = &smem[16384 + p * 8192];
    bf16x8 bf[2][2], af[8][2];
#pragma unroll
    for (int n = 0; n < 2; n++)
#pragma unroll
      for (int s = 0; s < 2; s++) {
        int rowB = w * 32 + n * 16 + lr;
        bf[n][s] = ldfrag(&Br[rowB * 64 + (((s * 4 + lk) ^ (lr & 7)) * 8)]);
      }
#pragma unroll
    for (int f = 0; f < 8; f++)
#pragma unroll
      for (int s = 0; s < 2; s++) {
        int rowA = f * 16 + lr;
        af[f][s] = ldfrag(&Ar[rowA * 64 + (((s * 4 + lk) ^ (lr & 7)) * 8)]);
      }
    __builtin_amdgcn_s_setprio(1);
#pragma unroll
    for (int f = 0; f < 8; f++)
#pragma unroll
      for (int n = 0; n < 2; n++)
#pragma unroll
        for (int s = 0; s < 2; s++)
          acc[f][n] = mfma16(af[f][s], bf[n][s], acc[f][n]);
    __builtin_amdgcn_s_setprio(0);
    asm volatile("s_waitcnt vmcnt(0)" ::: "memory");
    blockbar();
  }

  int ocol0 = colBlk + w * 32;
#pragma unroll
  for (int n = 0; n < 2; n++) {
    int c = ocol0 + n * 16 + lr;
    float bv = bias[c];
#pragma unroll
    for (int f = 0; f < 8; f++) {
      int r0 = rowBlk + f * 16 + lk * 4;
#pragma unroll
      for (int j = 0; j < 4; j++) {
        float v = acc[f][n][j] + bv;
        if (OUTF32) v += res[(size_t)(r0 + j) * N + c];
        if (RELU) v = fmaxf(v, 0.f);
        if (OUTF32) outF[(size_t)(r0 + j) * N + c] = v;
        else        outB[(size_t)(r0 + j) * N + c] = f2bf(v);
      }
    }
  }
}

// ---------------- flash attention: 8 waves, QBLK=128, KBLK=64, split-K pairs ----
// SPLIT=0: grid 256 = 16 bh * 16 qtiles, full key range, writes normalized bf16 O.
// SPLIT=1 (causal only): grid 512 = 16 qt(desc) * 2 half * 16 bh; block does half
//   of qt's key range (qt+1 tiles); writes unnormalized f32 partial O + (m,l).
template<int CAUSAL, int SPLIT>
__global__ __launch_bounds__(512, 2)
void attn8w(const u16* __restrict__ Qp, int qstride,
            const u16* __restrict__ Kp, int kstride,
            const u16* __restrict__ Vt, u16* __restrict__ O,
            float* __restrict__ Op, float* __restrict__ ml)
{
  __shared__ __align__(16) u16 smem[65536];   // 128KB

  int bidx = blockIdx.x;
  int bh, qt, kt0, kt1;
  if (SPLIT) {
    int qtIdx = bidx >> 5;         // 0..15, longest-first
    qt = 15 - qtIdx;
    int sub = bidx & 31;
    int half = sub >> 4;
    bh = sub & 15;
    kt0 = half ? (qt + 1) : 0;
    kt1 = half ? (2 * qt + 2) : (qt + 1);
  } else {
    bh = bidx & 15;
    qt = CAUSAL ? (15 - (bidx >> 4)) : (bidx >> 4);
    kt0 = 0;
    kt1 = CAUSAL ? (2 * qt + 2) : (NS / 64);
  }
  int b = bh >> 2, h = bh & 3;
  int tid = threadIdx.x, w = tid >> 6, lane = tid & 63;
  int L = lane & 31, hi = lane >> 5;
  int g = w >> 1, ks = w & 1;

  int qbase = qt * 128 + g * 32;

  const u16* qrow = Qp + (size_t)(b * NS + qbase + L) * qstride + h * NDH;
  bf16x8 qf[16];
#pragma unroll
  for (int s = 0; s < 16; s++) qf[s] = ldfrag(qrow + s * 16 + hi * 8);

  f32x16 oacc[8];
#pragma unroll
  for (int db = 0; db < 8; db++) oacc[db] = (f32x16){};
  float m = -1e30f, l = 0.f;

  constexpr float SC = 1.0f / NDH;

  const u16* kbase = Kp + (size_t)(b * NS) * kstride + h * NDH;
  const u16* vbase = Vt + (size_t)bh * NDH * NS;

  auto stage = [&](int kt, int buf) {
#pragma unroll
    for (int ii = 0; ii < 4; ii++) {
      int gi = w * 4 + ii;                       // 0..31
      int krow = 2 * gi + hi;
      int kcol = L ^ (krow & 31);
      gload_lds16(kbase + (size_t)(kt * 64 + krow) * kstride + kcol * 8,
                  &smem[buf * 16384 + gi * 512]);
      int vd = gi * 8 + (lane >> 3);
      int vg = (lane & 7) ^ (vd & 7);
      gload_lds16(vbase + (size_t)vd * NS + kt * 64 + vg * 8,
                  &smem[32768 + buf * 16384 + gi * 512]);
    }
  };

  stage(kt0, 0);
  asm volatile("" ::: "memory");     // group-order fence (R9 lesson)

  for (int kt = kt0; kt < kt1; kt++) {
    int buf = (kt - kt0) & 1;
    const u16* bK = &smem[buf * 16384];
    const u16* bV = &smem[32768 + buf * 16384];
    if (kt + 1 < kt1) {
      stage(kt + 1, buf ^ 1);
      asm volatile("s_waitcnt vmcnt(8)" ::: "memory");
    } else {
      asm volatile("s_waitcnt vmcnt(0)" ::: "memory");
    }
    blockbar();

    int ksub0 = kt * 64 + ks * 32;
    bool skip = CAUSAL && (ksub0 > qbase + 31);
    if (!skip) {
      bool domask = CAUSAL && (ksub0 + 31 > qbase);
      __builtin_amdgcn_s_setprio(1);
      f32x16 sa = (f32x16){};
#pragma unroll
      for (int s = 0; s < 16; s++) {
        int row = ks * 32 + L;
        bf16x8 kf = ldfrag(&bK[row * 256 + (((2 * s + hi) ^ L) & 31) * 8]);
        sa = mfma32(kf, qf[s], sa);
      }
      __builtin_amdgcn_s_setprio(0);

      float p[16];
      float tmax = -1e30f;
#pragma unroll
      for (int r = 0; r < 16; r++) {
        float v = sa[r] * SC;
        if (domask) {
          int key = ksub0 + (r & 3) + 8 * (r >> 2) + 4 * hi;
          if (key > qbase + L) v = -1e30f;
        }
        p[r] = v;
        tmax = fmaxf(tmax, v);
      }
      tmax = fmaxf(tmax, __shfl_xor(tmax, 32));

      float mn = m;
      if (!__all(tmax - m <= 5.0f)) {
        mn = fmaxf(m, tmax);
        float rs = __expf(m - mn);
        m = mn;
        l *= rs;
#pragma unroll
        for (int db = 0; db < 8; db++)
#pragma unroll
          for (int r = 0; r < 16; r++) oacc[db][r] *= rs;
      }
      float psum = 0.f;
#pragma unroll
      for (int r = 0; r < 16; r++) {
        p[r] = __expf(p[r] - mn);
        psum += p[r];
      }
      psum += __shfl_xor(psum, 32);
      l += psum;

      unsigned pk01 = packbf(p[0], p[1]),  pk23 = packbf(p[2], p[3]);
      unsigned pk45 = packbf(p[4], p[5]),  pk67 = packbf(p[6], p[7]);
      unsigned pk89 = packbf(p[8], p[9]),  pkab = packbf(p[10], p[11]);
      unsigned pkcd = packbf(p[12], p[13]), pkef = packbf(p[14], p[15]);
      unsigned s45 = (unsigned)__shfl_xor((int)pk45, 32);
      unsigned s67 = (unsigned)__shfl_xor((int)pk67, 32);
      unsigned s01 = (unsigned)__shfl_xor((int)pk01, 32);
      unsigned s23 = (unsigned)__shfl_xor((int)pk23, 32);
      unsigned scd = (unsigned)__shfl_xor((int)pkcd, 32);
      unsigned sef = (unsigned)__shfl_xor((int)pkef, 32);
      unsigned s89 = (unsigned)__shfl_xor((int)pk89, 32);
      unsigned sab = (unsigned)__shfl_xor((int)pkab, 32);
      union { unsigned u[4]; bf16x8 v; } fb0, fb1;
      fb0.u[0] = hi ? s45 : pk01;
      fb0.u[1] = hi ? s67 : pk23;
      fb0.u[2] = hi ? pk45 : s01;
      fb0.u[3] = hi ? pk67 : s23;
      fb1.u[0] = hi ? scd : pk89;
      fb1.u[1] = hi ? sef : pkab;
      fb1.u[2] = hi ? pkcd : s89;
      fb1.u[3] = hi ? pkef : sab;
      bf16x8 pb0 = fb0.v, pb1 = fb1.v;

      __builtin_amdgcn_s_setprio(1);
#pragma unroll
      for (int db = 0; db < 8; db++) {
        int vd = db * 32 + L;
        bf16x8 vf0 = ldfrag(&bV[vd * 64 + (((ks * 4 + hi) ^ (vd & 7)) & 7) * 8]);
        bf16x8 vf1 = ldfrag(&bV[vd * 64 + (((ks * 4 + 2 + hi) ^ (vd & 7)) & 7) * 8]);
        oacc[db] = mfma32(vf0, pb0, oacc[db]);
        oacc[db] = mfma32(vf1, pb1, oacc[db]);
      }
      __builtin_amdgcn_s_setprio(0);
    }
    blockbar();
  }

  // ---- merge wave pairs (w, w^1): disjoint keys, same 32 q-rows ----
  float* fsm = (float*)smem;
  blockbar();
  if (hi == 0) { fsm[w * 64 + L * 2] = m; fsm[w * 64 + L * 2 + 1] = l; }
  asm volatile("s_waitcnt lgkmcnt(0)" ::: "memory");
  blockbar();
  float mb = fsm[(w ^ 1) * 64 + L * 2];
  float lb = fsm[(w ^ 1) * 64 + L * 2 + 1];
  float M = fmaxf(m, mb);
  float eo = __expf(m - M);
  float lt = l * eo + lb * __expf(mb - M);
  asm volatile("s_waitcnt lgkmcnt(0)" ::: "memory");
  blockbar();
  float* reg = fsm + g * 8192;   // 32KB region per pair: [256 d][32 q] f32
  if (w & 1) {
#pragma unroll
    for (int db = 0; db < 8; db++)
#pragma unroll
      for (int r = 0; r < 16; r++) {
        int d = db * 32 + (r & 3) + 8 * (r >> 2) + 4 * hi;
        reg[d * 32 + L] = oacc[db][r] * eo;
      }
  }
  asm volatile("s_waitcnt lgkmcnt(0)" ::: "memory");
  blockbar();
  if (!(w & 1)) {
    if (SPLIT) {
      float* OpB = Op + (size_t)bidx * 32768 + (size_t)(g * 32 + L) * 256;
      if (hi == 0) {
        ml[((size_t)bidx * 128 + g * 32 + L) * 2]     = M;
        ml[((size_t)bidx * 128 + g * 32 + L) * 2 + 1] = lt;
      }
#pragma unroll
      for (int db = 0; db < 8; db++) {
#pragma unroll
        for (int rq = 0; rq < 4; rq++) {
          int d0 = db * 32 + rq * 8 + hi * 4;
          float4 v;
          v.x = oacc[db][rq * 4 + 0] * eo + reg[(d0 + 0) * 32 + L];
          v.y = oacc[db][rq * 4 + 1] * eo + reg[(d0 + 1) * 32 + L];
          v.z = oacc[db][rq * 4 + 2] * eo + reg[(d0 + 2) * 32 + L];
          v.w = oacc[db][rq * 4 + 3] * eo + reg[(d0 + 3) * 32 + L];
          *(float4*)(OpB + d0) = v;
        }
      }
    } else {
      float inv = 1.f / lt;
      size_t orow = (size_t)(b * NS + qbase + L) * NE + h * NDH;
#pragma unroll
      for (int db = 0; db < 8; db++) {
#pragma unroll
        for (int rq = 0; rq < 4; rq++) {
          int d0 = db * 32 + rq * 8 + hi * 4;
          float a0 = (oacc[db][rq * 4 + 0] * eo + reg[(d0 + 0) * 32 + L]) * inv;
          float a1 = (oacc[db][rq * 4 + 1] * eo + reg[(d0 + 1) * 32 + L]) * inv;
          float a2 = (oacc[db][rq * 4 + 2] * eo + reg[(d0 + 2) * 32 + L]) * inv;
          float a3 = (oacc[db][rq * 4 + 3] * eo + reg[(d0 + 3) * 32 + L]) * inv;
          uint2 wv;
          wv.x = packbf(a0, a1);
          wv.y = packbf(a2, a3);
          *(uint2*)&O[orow + d0] = wv;
        }
      }
    }
  }
}

// ---------------- merge the 2 split-K partials -> normalized bf16 O ----------------
__global__ __launch_bounds__(256)
void merge_attn(const float* __restrict__ Op, const float* __restrict__ ml,
                u16* __restrict__ O)
{
  int blk = blockIdx.x;
  int qt = blk >> 4, bh = blk & 15;
  int b = bh >> 2, h = bh & 3;
  int p0 = (15 - qt) * 32 + bh;
  int p1 = p0 + 16;
  int tid = threadIdx.x;
  int row = tid >> 1;
  int dbase = (tid & 1) * 128;

  float m0 = ml[((size_t)p0 * 128 + row) * 2];
  float l0 = ml[((size_t)p0 * 128 + row) * 2 + 1];
  float m1 = ml[((size_t)p1 * 128 + row) * 2];
  float l1 = ml[((size_t)p1 * 128 + row) * 2 + 1];
  float M = fmaxf(m0, m1);
  float e0 = __expf(m0 - M), e1 = __expf(m1 - M);
  float inv = 1.f / (l0 * e0 + l1 * e1);
  const float* O0 = Op + ((size_t)p0 * 128 + row) * 256 + dbase;
  const float* O1 = Op + ((size_t)p1 * 128 + row) * 256 + dbase;
  u16* dst = O + (size_t)(b * NS + qt * 128 + row) * NE + h * NDH + dbase;
#pragma unroll
  for (int d = 0; d < 128; d += 4) {
    float4 a = *(const float4*)(O0 + d);
    float4 c = *(const float4*)(O1 + d);
    uint2 wv;
    wv.x = packbf((a.x * e0 + c.x * e1) * inv, (a.y * e0 + c.y * e1) * inv);
    wv.y = packbf((a.z * e0 + c.z * e1) * inv, (a.w * e0 + c.w * e1) * inv);
    *(uint2*)(dst + d) = wv;
  }
}

// ---------------- LayerNorm (eps=1e-3), optional relu, optional bf16 copy ----------------
template<int RELU, int WBF>
__global__ __launch_bounds__(256)
void ln_kernel(const float* __restrict__ x, const float* __restrict__ g,
               const float* __restrict__ bb, float* __restrict__ outF,
               u16* __restrict__ outB)
{
  int row = blockIdx.x, tid = threadIdx.x;
  float4 v = ((const float4*)(x + (size_t)row * NE))[tid];
  float s = v.x + v.y + v.z + v.w;
  float s2 = v.x * v.x + v.y * v.y + v.z * v.z + v.w * v.w;
#pragma unroll
  for (int off = 32; off; off >>= 1) {
    s += __shfl_xor(s, off);
    s2 += __shfl_xor(s2, off);
  }
  __shared__ float red[8];
  int wid = tid >> 6, lane = tid & 63;
  if (lane == 0) { red[wid] = s; red[4 + wid] = s2; }
  __syncthreads();
  s = red[0] + red[1] + red[2] + red[3];
  s2 = red[4] + red[5] + red[6] + red[7];
  float mean = s * (1.f / NE);
  float var = s2 * (1.f / NE) - mean * mean;
  float rstd = rsqrtf(var + 1e-3f);
  float4 gg = ((const float4*)g)[tid];
  float4 bv = ((const float4*)bb)[tid];
  float4 o;
  o.x = (v.x - mean) * rstd * gg.x + bv.x;
  o.y = (v.y - mean) * rstd * gg.y + bv.y;
  o.z = (v.z - mean) * rstd * gg.z + bv.z;
  o.w = (v.w - mean) * rstd * gg.w + bv.w;
  if (RELU) {
    o.x = fmaxf(o.x, 0.f); o.y = fmaxf(o.y, 0.f);
    o.z = fmaxf(o.z, 0.f); o.w = fmaxf(o.w, 0.f);
  }
  ((float4*)(outF + (size_t)row * NE))[tid] = o;
  if (WBF) {
    ushort4 ob;
    ob.x = f2bf(o.x); ob.y = f2bf(o.y); ob.z = f2bf(o.z); ob.w = f2bf(o.w);
    ((ushort4*)(outB + (size_t)row * NE))[tid] = ob;
  }
}

// ---------------- workspace layout (bytes) ----------------
constexpr size_t OFF_X    = 0;                       // 16 MB: Xbf -> O1 -> Ctxbf -> O2
constexpr size_t OFF_W    = OFF_X + 16777216;        // 32 MB packed weights
constexpr size_t OFF_BIAS = OFF_W + 33554432;        // packed biases
constexpr size_t OFF_QKV  = OFF_BIAS + 32768;        // 48 MB QKV1 / (KV2 + Q2) / MID
constexpr size_t OFF_VT   = OFF_QKV + 50331648;      // 16 MB Vt
constexpr size_t OFF_T0   = OFF_VT + 16777216;       // 32 MB f32 scratch; +Af = 64MB Op during attn1
constexpr size_t OFF_A    = OFF_T0 + 33554432;       // 32 MB f32 a / c
constexpr size_t OFF_ABF  = OFF_A + 33554432;        // 16 MB bf16 a / c; ml during attn1

extern "C" void kernel_launch(void* const* d_in, const int* in_sizes, int n_in,
                              void* d_out, int out_size, void* d_ws, size_t ws_size,
                              hipStream_t stream) {
  (void)in_sizes; (void)n_in; (void)out_size; (void)ws_size;
  const float* inp = (const float*)d_in[0];
  const float* ctx = (const float*)d_in[1];
  const float* Wk1 = (const float*)d_in[2];  const float* bk1 = (const float*)d_in[3];
  const float* Wq1 = (const float*)d_in[4];  const float* bq1 = (const float*)d_in[5];
  const float* Wv1 = (const float*)d_in[6];  const float* bv1 = (const float*)d_in[7];
  const float* Wo1 = (const float*)d_in[8];  const float* bo1 = (const float*)d_in[9];
  const float* Wk2 = (const float*)d_in[10]; const float* bk2 = (const float*)d_in[11];
  const float* Wq2 = (const float*)d_in[12]; const float* bq2 = (const float*)d_in[13];
  const float* Wv2 = (const float*)d_in[14]; const float* bv2 = (const float*)d_in[15];
  const float* Wo2 = (const float*)d_in[16]; const float* bo2 = (const float*)d_in[17];
  const float* lng = (const float*)d_in[18]; const float* lnb = (const float*)d_in[19];
  const float* W1  = (const float*)d_in[20]; const float* b1  = (const float*)d_in[21];
  const float* W2  = (const float*)d_in[22]; const float* b2  = (const float*)d_in[23];
  float* out = (float*)d_out;
  char* ws = (char*)d_ws;

  u16* XBF    = (u16*)(ws + OFF_X);        // also ctx-bf16 and attention-O buffer
  u16* WQKV1T = (u16*)(ws + OFF_W);        // rows [K|Q|V] x 1024
  u16* WKV2T  = WQKV1T + 3072 * 1024;      // rows [K|V] x 1024
  u16* WQ2T   = WKV2T + 2048 * 1024;
  u16* WO1T   = WQ2T + 1024 * 1024;
  u16* WO2T   = WO1T + 1024 * 1024;
  u16* W1T    = WO2T + 1024 * 1024;        // [4096][1024]
  u16* W2T    = W1T + 4096 * 1024;         // [1024][4096]
  float* BQKV1 = (float*)(ws + OFF_BIAS);  // 3072
  float* BKV2  = BQKV1 + 3072;             // 2048
  u16* QKV  = (u16*)(ws + OFF_QKV);        // [8192][3072] (self) / [8192][2048] KV2
  u16* Q2   = QKV + 8192 * 2048;           // [8192][1024]
  u16* VT   = (u16*)(ws + OFF_VT);         // [16][256][2048]
  u16* MID  = QKV;                         // [8192][4096] (aliases QKV+VT, both dead)
  float* T0 = (float*)(ws + OFF_T0);
  float* OpBuf = T0;                       // 64MB partial O (T0+Af, both dead in attn1)
  float* Af = (float*)(ws + OFF_A);
  u16* ABF  = (u16*)(ws + OFF_ABF);
  float* MlBuf = (float*)(ws + OFF_ABF);   // 512KB (ABF dead in attn1)
  u16* Obuf = XBF;

  dim3 tb(32, 8);

  // input cast + packed weight/bias preprocessing (5 dispatches)
  cast_f32_bf16<<<8192, 256, 0, stream>>>(inp, XBF, NR * NE / 4);
  transpose_cast6<<<dim3(8, 32, 24), tb, 0, stream>>>(
      Wk1, Wq1, Wv1, Wk2, Wv2, Wq2,
      WQKV1T, WQKV1T + 1024 * 1024, WQKV1T + 2048 * 1024,
      WKV2T, WKV2T + 1024 * 1024, WQ2T);
  transpose_cast2<<<dim3(32, 32, 2), tb, 0, stream>>>(Wo1, Wo2, WO1T, WO2T);
  transpose_cast<<<dim3(128, 32, 1), tb, 0, stream>>>(W1, W1T, NE, NF);
  transpose_cast<<<dim3(32, 128, 1), tb, 0, stream>>>(W2, W2T, NF, NE);
  pack_bias<<<20, 256, 0, stream>>>(bk1, bq1, bv1, bk2, bv2, BQKV1, BKV2);

  // ---- self-attention block (split-K balanced causal) ----
  gemm2b<0, 0><<<dim3(24, 64), 256, 0, stream>>>(XBF, WQKV1T, BQKV1, nullptr,
                                                 nullptr, QKV, NR, 3072, NE);
  transpose_v<<<dim3(64, 8, 16), tb, 0, stream>>>(QKV + 2048, 3072, VT);
  attn8w<1, 1><<<512, 512, 0, stream>>>(QKV + 1024, 3072, QKV, 3072, VT,
                                        nullptr, OpBuf, MlBuf);
  merge_attn<<<256, 256, 0, stream>>>(OpBuf, MlBuf, Obuf);
  gemm2b<1, 0><<<dim3(8, 64), 256, 0, stream>>>(Obuf, WO1T, bo1, inp,
                                                T0, nullptr, NR, NE, NE);
  ln_kernel<0, 1><<<NR, 256, 0, stream>>>(T0, lng, lnb, Af, ABF);

  // ---- cross-attention block ----
  cast_f32_bf16<<<8192, 256, 0, stream>>>(ctx, XBF, NR * NE / 4);
  gemm2b<0, 0><<<dim3(16, 64), 256, 0, stream>>>(XBF, WKV2T, BKV2, nullptr,
                                                 nullptr, QKV, NR, 2048, NE);
  gemm2b<0, 0><<<dim3(8, 64), 256, 0, stream>>>(ABF, WQ2T, bq2, nullptr,
                                                nullptr, Q2, NR, NE, NE);
  transpose_v<<<dim3(64, 8, 16), tb, 0, stream>>>(QKV + 1024, 2048, VT);
  attn8w<0, 0><<<256, 512, 0, stream>>>(Q2, 1024, QKV, 2048, VT, Obuf,
                                        nullptr, nullptr);
  gemm2b<1, 0><<<dim3(8, 64), 256, 0, stream>>>(Obuf, WO2T, bo2, Af,
                                                T0, nullptr, NR, NE, NE);
  ln_kernel<0, 1><<<NR, 256, 0, stream>>>(T0, lng, lnb, Af, ABF);

  // ---- FFN ----
  gemm2b<0, 1><<<dim3(32, 64), 256, 0, stream>>>(ABF, W1T, b1, nullptr,
                                                 nullptr, MID, NR, NF, NE);
  gemm2b<1, 0><<<dim3(8, 64), 256, 0, stream>>>(MID, W2T, b2, Af,
                                                T0, nullptr, NR, NE, NF);
  ln_kernel<1, 0><<<NR, 256, 0, stream>>>(T0, lng, lnb, out, nullptr);
}